// Round 1
// baseline (211.813 us; speedup 1.0000x reference)
//
#include <hip/hip_runtime.h>
#include <hip/hip_bf16.h>
#include <math.h>

typedef __attribute__((ext_vector_type(8))) short short8;   // 8 bf16 (4 VGPRs)
typedef __attribute__((ext_vector_type(4))) float f32x4;    // MFMA C/D

#define BM 128
#define BN 128
#define BK 32

// ---------------------------------------------------------------------------
// prep: one block (64 threads = 1 wave) per row. Converts fp32 row -> bf16,
// computes ||row||^2 in fp32. D=512 -> each lane handles exactly 8 elements.
// ---------------------------------------------------------------------------
__global__ void prep_kernel(const float* __restrict__ in,
                            __hip_bfloat16* __restrict__ outb,
                            float* __restrict__ sq, int Dv) {
    const int row  = blockIdx.x;
    const int lane = threadIdx.x;  // 64
    const float* rp = in + (size_t)row * Dv;
    __hip_bfloat16* op = outb + (size_t)row * Dv;

    float acc = 0.f;
    for (int k = lane * 8; k < Dv; k += 64 * 8) {
        float4 v0 = *(const float4*)(rp + k);
        float4 v1 = *(const float4*)(rp + k + 4);
        acc += v0.x * v0.x + v0.y * v0.y + v0.z * v0.z + v0.w * v0.w;
        acc += v1.x * v1.x + v1.y * v1.y + v1.z * v1.z + v1.w * v1.w;
        union { __hip_bfloat16 h[8]; uint4 u; } pk;
        pk.h[0] = __float2bfloat16(v0.x);
        pk.h[1] = __float2bfloat16(v0.y);
        pk.h[2] = __float2bfloat16(v0.z);
        pk.h[3] = __float2bfloat16(v0.w);
        pk.h[4] = __float2bfloat16(v1.x);
        pk.h[5] = __float2bfloat16(v1.y);
        pk.h[6] = __float2bfloat16(v1.z);
        pk.h[7] = __float2bfloat16(v1.w);
        *(uint4*)(op + k) = pk.u;
    }
#pragma unroll
    for (int off = 1; off < 64; off <<= 1)
        acc += __shfl_xor(acc, off, 64);
    if (lane == 0) sq[row] = acc;
}

// ---------------------------------------------------------------------------
// Fused GEMM + exp-reduce. Block: 256 threads (4 waves, 2x2), tile 128x128,
// BK=32, 16x16x32 bf16 MFMA, global_load_lds width-16 staging.
// Epilogue: t = exp(-scale*max(x2+s2-2*dot,0)); row-reduce; atomicAdd.
// ---------------------------------------------------------------------------
__global__ __launch_bounds__(256) void kde_gemm_kernel(
    const __hip_bfloat16* __restrict__ Xb,   // [M][D]
    const __hip_bfloat16* __restrict__ Sb,   // [N][D]
    const float* __restrict__ x2,
    const float* __restrict__ s2,
    const float* __restrict__ scale_p,
    float* __restrict__ rowsum,
    int M, int N, int Dv)
{
    __shared__ __hip_bfloat16 As[BM * BK];   // 8 KB, row-major [128][32]
    __shared__ __hip_bfloat16 Bs[BN * BK];   // 8 KB

    const int tid  = threadIdx.x;
    const int wave = tid >> 6;
    const int lane = tid & 63;
    const int quad = lane >> 4;
    const int l16  = lane & 15;

    const int m0 = blockIdx.x * BM;
    const int n0 = blockIdx.y * BN;

    const int wm = (wave & 1) * 64;   // wave's 64x64 quadrant
    const int wn = (wave >> 1) * 64;

    f32x4 acc[4][4] = {};

    // staging map: thread t covers (row = (t>>2) + 64*round, kchunk = (t&3)*8)
    // LDS offset = t*16 bytes = wave-uniform base (wave*1024 + round*4096) + lane*16
    const int srow = tid >> 2;
    const int skc  = (tid & 3) * 8;
    const size_t aRowBase = (size_t)(m0 + srow) * Dv + skc;
    const size_t bRowBase = (size_t)(n0 + srow) * Dv + skc;

    for (int k0 = 0; k0 < Dv; k0 += BK) {
        __syncthreads();  // previous iter's ds_reads done before overwrite
        {
            const __hip_bfloat16* ga0 = Xb + aRowBase + k0;
            const __hip_bfloat16* ga1 = Xb + aRowBase + (size_t)64 * Dv + k0;
            const __hip_bfloat16* gb0 = Sb + bRowBase + k0;
            const __hip_bfloat16* gb1 = Sb + bRowBase + (size_t)64 * Dv + k0;
            __hip_bfloat16* la0 = As + wave * 512;          // bytes: wave*1024
            __hip_bfloat16* la1 = As + 2048 + wave * 512;   // + round*4096B
            __hip_bfloat16* lb0 = Bs + wave * 512;
            __hip_bfloat16* lb1 = Bs + 2048 + wave * 512;
            __builtin_amdgcn_global_load_lds(
                (const __attribute__((address_space(1))) void*)ga0,
                (__attribute__((address_space(3))) void*)la0, 16, 0, 0);
            __builtin_amdgcn_global_load_lds(
                (const __attribute__((address_space(1))) void*)ga1,
                (__attribute__((address_space(3))) void*)la1, 16, 0, 0);
            __builtin_amdgcn_global_load_lds(
                (const __attribute__((address_space(1))) void*)gb0,
                (__attribute__((address_space(3))) void*)lb0, 16, 0, 0);
            __builtin_amdgcn_global_load_lds(
                (const __attribute__((address_space(1))) void*)gb1,
                (__attribute__((address_space(3))) void*)lb1, 16, 0, 0);
        }
        __syncthreads();  // staging drained (vmcnt(0) before s_barrier)

        short8 a_frag[4], b_frag[4];
#pragma unroll
        for (int mi = 0; mi < 4; ++mi)
            a_frag[mi] = *(const short8*)(As + (wm + mi * 16 + l16) * BK + quad * 8);
#pragma unroll
        for (int ni = 0; ni < 4; ++ni)
            b_frag[ni] = *(const short8*)(Bs + (wn + ni * 16 + l16) * BK + quad * 8);
#pragma unroll
        for (int mi = 0; mi < 4; ++mi)
#pragma unroll
            for (int ni = 0; ni < 4; ++ni)
                acc[mi][ni] = __builtin_amdgcn_mfma_f32_16x16x32_bf16(
                    a_frag[mi], b_frag[ni], acc[mi][ni], 0, 0, 0);
    }

    // ---- epilogue: C layout col = lane&15 (-> n), row = quad*4 + reg (-> m)
    const float sc = *scale_p;
    float s2v[4];
#pragma unroll
    for (int ni = 0; ni < 4; ++ni)
        s2v[ni] = s2[n0 + wn + ni * 16 + l16];

#pragma unroll
    for (int mi = 0; mi < 4; ++mi) {
#pragma unroll
        for (int r = 0; r < 4; ++r) {
            const int m = m0 + wm + mi * 16 + quad * 4 + r;
            const float xv = x2[m];
            float sum = 0.f;
#pragma unroll
            for (int ni = 0; ni < 4; ++ni) {
                float d2 = xv + s2v[ni] - 2.0f * acc[mi][ni][r];
                d2 = fmaxf(d2, 0.f);
                sum += __expf(-sc * d2);
            }
            // reduce the 16 column-lanes (xor 1,2,4,8 stays within quad)
#pragma unroll
            for (int off = 1; off < 16; off <<= 1)
                sum += __shfl_xor(sum, off, 64);
            if (l16 == 0) atomicAdd(&rowsum[m], sum);
        }
    }
}

// ---------------------------------------------------------------------------
__global__ void finalize_kernel(const float* __restrict__ rowsum,
                                const float* __restrict__ scale_p,
                                float* __restrict__ out, int M, int N, int Dv) {
    const int m = blockIdx.x * 256 + threadIdx.x;
    if (m < M) {
        const float sc = *scale_p;
        const float cst = -logf((float)N) + 0.5f * (float)Dv * logf(sc / 3.14159265358979f);
        out[m] = logf(rowsum[m]) + cst;
    }
}

// ---------------------------------------------------------------------------
extern "C" void kernel_launch(void* const* d_in, const int* in_sizes, int n_in,
                              void* d_out, int out_size, void* d_ws, size_t ws_size,
                              hipStream_t stream) {
    const float* X       = (const float*)d_in[0];
    const float* S       = (const float*)d_in[1];
    const float* scale_p = (const float*)d_in[2];
    float* out = (float*)d_out;

    const int M  = out_size;            // 8192
    const int Dv = in_sizes[0] / M;     // 512
    const int N  = in_sizes[1] / Dv;    // 8192

    char* ws = (char*)d_ws;
    __hip_bfloat16* Xb = (__hip_bfloat16*)ws;
    __hip_bfloat16* Sb = (__hip_bfloat16*)(ws + (size_t)M * Dv * 2);
    float* x2     = (float*)(ws + (size_t)M * Dv * 2 + (size_t)N * Dv * 2);
    float* s2     = x2 + M;
    float* rowsum = s2 + N;

    prep_kernel<<<M, 64, 0, stream>>>(X, Xb, x2, Dv);
    prep_kernel<<<N, 64, 0, stream>>>(S, Sb, s2, Dv);
    hipMemsetAsync(rowsum, 0, (size_t)M * sizeof(float), stream);

    dim3 grid(M / BM, N / BN);
    kde_gemm_kernel<<<grid, 256, 0, stream>>>(Xb, Sb, x2, s2, scale_p, rowsum, M, N, Dv);

    finalize_kernel<<<(M + 255) / 256, 256, 0, stream>>>(rowsum, scale_p, out, M, N, Dv);
}

// Round 2
// 149.928 us; speedup vs baseline: 1.4128x; 1.4128x over previous
//
#include <hip/hip_runtime.h>
#include <hip/hip_bf16.h>
#include <math.h>

typedef __attribute__((ext_vector_type(8))) short short8;   // 8 bf16 (4 VGPRs)
typedef __attribute__((ext_vector_type(4))) float f32x4;    // MFMA C/D

#define BM 128
#define BN 128
#define BK 64

// ---------------------------------------------------------------------------
// prep: one wave per row, rows [0,M) -> X, rows [M,M+N) -> svs.
// fp32 -> bf16 + ||row||^2.
// ---------------------------------------------------------------------------
__global__ void prep_kernel(const float* __restrict__ X,
                            const float* __restrict__ S,
                            __hip_bfloat16* __restrict__ Xb,
                            __hip_bfloat16* __restrict__ Sb,
                            float* __restrict__ x2,
                            float* __restrict__ s2,
                            int M, int Dv) {
    const int row  = blockIdx.x;
    const int lane = threadIdx.x;  // 64
    const float* rp;
    __hip_bfloat16* op;
    float* sq;
    if (row < M) { rp = X + (size_t)row * Dv;       op = Xb + (size_t)row * Dv;       sq = x2 + row; }
    else         { rp = S + (size_t)(row - M) * Dv; op = Sb + (size_t)(row - M) * Dv; sq = s2 + (row - M); }

    float acc = 0.f;
    for (int k = lane * 8; k < Dv; k += 64 * 8) {
        float4 v0 = *(const float4*)(rp + k);
        float4 v1 = *(const float4*)(rp + k + 4);
        acc += v0.x * v0.x + v0.y * v0.y + v0.z * v0.z + v0.w * v0.w;
        acc += v1.x * v1.x + v1.y * v1.y + v1.z * v1.z + v1.w * v1.w;
        union { __hip_bfloat16 h[8]; uint4 u; } pk;
        pk.h[0] = __float2bfloat16(v0.x);
        pk.h[1] = __float2bfloat16(v0.y);
        pk.h[2] = __float2bfloat16(v0.z);
        pk.h[3] = __float2bfloat16(v0.w);
        pk.h[4] = __float2bfloat16(v1.x);
        pk.h[5] = __float2bfloat16(v1.y);
        pk.h[6] = __float2bfloat16(v1.z);
        pk.h[7] = __float2bfloat16(v1.w);
        *(uint4*)(op + k) = pk.u;
    }
#pragma unroll
    for (int off = 1; off < 64; off <<= 1)
        acc += __shfl_xor(acc, off, 64);
    if (lane == 0) *sq = acc;
}

// ---------------------------------------------------------------------------
// Fused GEMM + exp-reduce. 256 threads (4 waves 2x2), tile 128x128, BK=64.
// XOR-swizzled LDS layout: global chunk j of row r lives at physical chunk
// j^(r&7). Staging fetches chunk (lane&7)^(row&7) so the linear lane*16B
// LDS order realizes that layout (global_load_lds wave-uniform-base rule).
// Epilogue: exp in C-layout -> LDS transpose (stride 20 pad) -> 1 coalesced
// atomicAdd per lane.
// ---------------------------------------------------------------------------
__global__ __launch_bounds__(256, 4) void kde_gemm_kernel(
    const __hip_bfloat16* __restrict__ Xb,   // [M][D]
    const __hip_bfloat16* __restrict__ Sb,   // [N][D]
    const float* __restrict__ x2,
    const float* __restrict__ s2,
    const float* __restrict__ scale_p,
    float* __restrict__ rowsum,
    int M, int N, int Dv)
{
    __shared__ char smem[32768];
    __hip_bfloat16* As = (__hip_bfloat16*)smem;            // [128][64] 16 KB
    __hip_bfloat16* Bs = (__hip_bfloat16*)(smem + 16384);  // [128][64] 16 KB

    const int tid  = threadIdx.x;
    const int wave = tid >> 6;
    const int lane = tid & 63;
    const int quad = lane >> 4;
    const int l16  = lane & 15;

    const int m0 = blockIdx.x * BM;
    const int n0 = blockIdx.y * BN;
    const int wm = (wave & 1) * 64;   // wave's 64x64 quadrant
    const int wn = (wave >> 1) * 64;

    const float sc = *scale_p;        // hoisted scalar load

    f32x4 acc[4][4] = {};

    // staging map: round rd covers rows rd*32..rd*32+31; thread handles
    // row = wave*8 + (lane>>3) + rd*32, fetching GLOBAL chunk (lane&7)^(row&7)
    // into physical slot lane&7. (row&7) == (lane>>3) for every round.
    const int srow0 = wave * 8 + (lane >> 3);
    const int cg    = (lane & 7) ^ (lane >> 3);
    const __hip_bfloat16* gA = Xb + (size_t)(m0 + srow0) * Dv + cg * 8;
    const __hip_bfloat16* gB = Sb + (size_t)(n0 + srow0) * Dv + cg * 8;

    for (int k0 = 0; k0 < Dv; k0 += BK) {
        __syncthreads();  // prev iter's ds_reads done before overwrite
#pragma unroll
        for (int rd = 0; rd < 4; ++rd)
            __builtin_amdgcn_global_load_lds(
                (const __attribute__((address_space(1))) void*)(gA + (size_t)rd * 32 * Dv + k0),
                (__attribute__((address_space(3))) void*)(smem + rd * 4096 + wave * 1024),
                16, 0, 0);
#pragma unroll
        for (int rd = 0; rd < 4; ++rd)
            __builtin_amdgcn_global_load_lds(
                (const __attribute__((address_space(1))) void*)(gB + (size_t)rd * 32 * Dv + k0),
                (__attribute__((address_space(3))) void*)(smem + 16384 + rd * 4096 + wave * 1024),
                16, 0, 0);
        __syncthreads();  // staging drained

#pragma unroll
        for (int ks = 0; ks < 2; ++ks) {
            short8 a_frag[4], b_frag[4];
            const int cph = ((ks * 4 + quad) ^ (l16 & 7)) * 8;  // r&7 == l16&7
#pragma unroll
            for (int mi = 0; mi < 4; ++mi)
                a_frag[mi] = *(const short8*)(As + (wm + mi * 16 + l16) * BK + cph);
#pragma unroll
            for (int ni = 0; ni < 4; ++ni)
                b_frag[ni] = *(const short8*)(Bs + (wn + ni * 16 + l16) * BK + cph);
#pragma unroll
            for (int mi = 0; mi < 4; ++mi)
#pragma unroll
                for (int ni = 0; ni < 4; ++ni)
                    acc[mi][ni] = __builtin_amdgcn_mfma_f32_16x16x32_bf16(
                        a_frag[mi], b_frag[ni], acc[mi][ni], 0, 0, 0);
        }
    }

    // ---- epilogue. C layout: col = l16 (-> n), row = quad*4 + reg (-> m).
    __syncthreads();  // all waves done reading As/Bs; reuse LDS
    float* wred = (float*)smem + wave * (64 * 20);  // 5120 B per wave

    float s2v[4];
#pragma unroll
    for (int ni = 0; ni < 4; ++ni)
        s2v[ni] = s2[n0 + wn + ni * 16 + l16];

#pragma unroll
    for (int mi = 0; mi < 4; ++mi) {
#pragma unroll
        for (int r = 0; r < 4; ++r) {
            const int rowL = mi * 16 + quad * 4 + r;
            const float xv = x2[m0 + wm + rowL];
            float sum = 0.f;
#pragma unroll
            for (int ni = 0; ni < 4; ++ni) {
                float d2 = xv + s2v[ni] - 2.0f * acc[mi][ni][r];
                d2 = fmaxf(d2, 0.f);
                sum += __expf(-sc * d2);
            }
            wred[rowL * 20 + l16] = sum;
        }
    }
    __syncthreads();  // order LDS writes before cross-lane reads

    float4 p0 = *(float4*)(wred + lane * 20 + 0);
    float4 p1 = *(float4*)(wred + lane * 20 + 4);
    float4 p2 = *(float4*)(wred + lane * 20 + 8);
    float4 p3 = *(float4*)(wred + lane * 20 + 12);
    float s = (p0.x + p0.y + p0.z + p0.w) + (p1.x + p1.y + p1.z + p1.w)
            + (p2.x + p2.y + p2.z + p2.w) + (p3.x + p3.y + p3.z + p3.w);
    atomicAdd(&rowsum[m0 + wm + lane], s);
}

// ---------------------------------------------------------------------------
__global__ void finalize_kernel(const float* __restrict__ rowsum,
                                const float* __restrict__ scale_p,
                                float* __restrict__ out, int M, int N, int Dv) {
    const int m = blockIdx.x * 256 + threadIdx.x;
    if (m < M) {
        const float sc = *scale_p;
        const float cst = -logf((float)N) + 0.5f * (float)Dv * logf(sc / 3.14159265358979f);
        out[m] = logf(rowsum[m]) + cst;
    }
}

// ---------------------------------------------------------------------------
extern "C" void kernel_launch(void* const* d_in, const int* in_sizes, int n_in,
                              void* d_out, int out_size, void* d_ws, size_t ws_size,
                              hipStream_t stream) {
    const float* X       = (const float*)d_in[0];
    const float* S       = (const float*)d_in[1];
    const float* scale_p = (const float*)d_in[2];
    float* out = (float*)d_out;

    const int M  = out_size;            // 8192
    const int Dv = in_sizes[0] / M;     // 512
    const int N  = in_sizes[1] / Dv;    // 8192

    char* ws = (char*)d_ws;
    __hip_bfloat16* Xb = (__hip_bfloat16*)ws;
    __hip_bfloat16* Sb = (__hip_bfloat16*)(ws + (size_t)M * Dv * 2);
    float* x2     = (float*)(ws + (size_t)M * Dv * 2 + (size_t)N * Dv * 2);
    float* s2     = x2 + M;
    float* rowsum = s2 + N;

    prep_kernel<<<M + N, 64, 0, stream>>>(X, S, Xb, Sb, x2, s2, M, Dv);
    hipMemsetAsync(rowsum, 0, (size_t)M * sizeof(float), stream);

    dim3 grid(M / BM, N / BN);
    kde_gemm_kernel<<<grid, 256, 0, stream>>>(Xb, Sb, x2, s2, scale_p, rowsum, M, N, Dv);

    finalize_kernel<<<(M + 255) / 256, 256, 0, stream>>>(rowsum, scale_p, out, M, N, Dv);
}

// Round 3
// 145.821 us; speedup vs baseline: 1.4526x; 1.0282x over previous
//
#include <hip/hip_runtime.h>
#include <hip/hip_bf16.h>
#include <math.h>

typedef __attribute__((ext_vector_type(8))) short short8;   // 8 bf16 (4 VGPRs)
typedef __attribute__((ext_vector_type(4))) float f32x4;    // MFMA C/D

#define BM 128
#define BN 128
#define BK 64

// ---------------------------------------------------------------------------
// prep: 512 blocks x 256 threads. Grid-stride over all M+N rows, one wave per
// row per iteration (8 rows/wave). fp32 -> bf16 + ||row||^2. Also zeroes
// rowsum[M] (replaces a separate hipMemsetAsync launch).
// ---------------------------------------------------------------------------
__global__ __launch_bounds__(256) void prep_kernel(
    const float* __restrict__ X, const float* __restrict__ S,
    __hip_bfloat16* __restrict__ Xb, __hip_bfloat16* __restrict__ Sb,
    float* __restrict__ x2, float* __restrict__ s2,
    float* __restrict__ rowsum, int M, int R, int Dv)
{
    const int gid  = blockIdx.x * 256 + threadIdx.x;
    const int nthr = gridDim.x * 256;

    // zero rowsum (stream-ordered before the GEMM's atomics)
    for (int i = gid; i < M; i += nthr) rowsum[i] = 0.f;

    const int lane = threadIdx.x & 63;
    const int wid  = gid >> 6;
    const int nw   = nthr >> 6;

    for (int row = wid; row < R; row += nw) {
        const float* rp;
        __hip_bfloat16* op;
        float* sq;
        if (row < M) { rp = X + (size_t)row * Dv;       op = Xb + (size_t)row * Dv;       sq = x2 + row; }
        else         { rp = S + (size_t)(row - M) * Dv; op = Sb + (size_t)(row - M) * Dv; sq = s2 + (row - M); }

        float acc = 0.f;
        for (int k = lane * 8; k < Dv; k += 64 * 8) {
            float4 v0 = *(const float4*)(rp + k);
            float4 v1 = *(const float4*)(rp + k + 4);
            acc += v0.x * v0.x + v0.y * v0.y + v0.z * v0.z + v0.w * v0.w;
            acc += v1.x * v1.x + v1.y * v1.y + v1.z * v1.z + v1.w * v1.w;
            union { __hip_bfloat16 h[8]; uint4 u; } pk;
            pk.h[0] = __float2bfloat16(v0.x);
            pk.h[1] = __float2bfloat16(v0.y);
            pk.h[2] = __float2bfloat16(v0.z);
            pk.h[3] = __float2bfloat16(v0.w);
            pk.h[4] = __float2bfloat16(v1.x);
            pk.h[5] = __float2bfloat16(v1.y);
            pk.h[6] = __float2bfloat16(v1.z);
            pk.h[7] = __float2bfloat16(v1.w);
            *(uint4*)(op + k) = pk.u;
        }
#pragma unroll
        for (int off = 1; off < 64; off <<= 1)
            acc += __shfl_xor(acc, off, 64);
        if (lane == 0) *sq = acc;
    }
}

// ---------------------------------------------------------------------------
// Fused GEMM + exp-reduce. 256 threads (4 waves 2x2), tile 128x128, BK=64.
// XOR-swizzled LDS (0 bank conflicts, verified R2). DVC=512 template fully
// unrolls the 8-iteration K-loop; DVC=0 is the runtime fallback.
// ---------------------------------------------------------------------------
template<int DVC>
__global__ __launch_bounds__(256, 4) void kde_gemm_kernel(
    const __hip_bfloat16* __restrict__ Xb,   // [M][D]
    const __hip_bfloat16* __restrict__ Sb,   // [N][D]
    const float* __restrict__ x2,
    const float* __restrict__ s2,
    const float* __restrict__ scale_p,
    float* __restrict__ rowsum,
    int M, int N, int Dv)
{
    const int D = DVC ? DVC : Dv;

    __shared__ char smem[32768];
    __hip_bfloat16* As = (__hip_bfloat16*)smem;            // [128][64] 16 KB
    __hip_bfloat16* Bs = (__hip_bfloat16*)(smem + 16384);  // [128][64] 16 KB

    const int tid  = threadIdx.x;
    const int wave = tid >> 6;
    const int lane = tid & 63;
    const int quad = lane >> 4;
    const int l16  = lane & 15;

    const int m0 = blockIdx.x * BM;
    const int n0 = blockIdx.y * BN;
    const int wm = (wave & 1) * 64;   // wave's 64x64 quadrant
    const int wn = (wave >> 1) * 64;

    const float sc = *scale_p;

    f32x4 acc[4][4] = {};

    // staging: round rd covers rows rd*32..rd*32+31; thread handles
    // row = wave*8 + (lane>>3) + rd*32, fetching GLOBAL chunk (lane&7)^(row&7)
    // into physical slot lane&7 (row&7 == lane>>3 every round).
    const int srow0 = wave * 8 + (lane >> 3);
    const int cg    = (lane & 7) ^ (lane >> 3);
    const __hip_bfloat16* gA = Xb + (size_t)(m0 + srow0) * D + cg * 8;
    const __hip_bfloat16* gB = Sb + (size_t)(n0 + srow0) * D + cg * 8;

#pragma unroll
    for (int k0 = 0; k0 < D; k0 += BK) {
        __syncthreads();  // prev iter's ds_reads done before overwrite
#pragma unroll
        for (int rd = 0; rd < 4; ++rd)
            __builtin_amdgcn_global_load_lds(
                (const __attribute__((address_space(1))) void*)(gA + (size_t)rd * 32 * D + k0),
                (__attribute__((address_space(3))) void*)(smem + rd * 4096 + wave * 1024),
                16, 0, 0);
#pragma unroll
        for (int rd = 0; rd < 4; ++rd)
            __builtin_amdgcn_global_load_lds(
                (const __attribute__((address_space(1))) void*)(gB + (size_t)rd * 32 * D + k0),
                (__attribute__((address_space(3))) void*)(smem + 16384 + rd * 4096 + wave * 1024),
                16, 0, 0);
        __syncthreads();  // staging drained

#pragma unroll
        for (int ks = 0; ks < 2; ++ks) {
            short8 a_frag[4], b_frag[4];
            const int cph = ((ks * 4 + quad) ^ (l16 & 7)) * 8;  // r&7 == l16&7
#pragma unroll
            for (int mi = 0; mi < 4; ++mi)
                a_frag[mi] = *(const short8*)(As + (wm + mi * 16 + l16) * BK + cph);
#pragma unroll
            for (int ni = 0; ni < 4; ++ni)
                b_frag[ni] = *(const short8*)(Bs + (wn + ni * 16 + l16) * BK + cph);
#pragma unroll
            for (int mi = 0; mi < 4; ++mi)
#pragma unroll
                for (int ni = 0; ni < 4; ++ni)
                    acc[mi][ni] = __builtin_amdgcn_mfma_f32_16x16x32_bf16(
                        a_frag[mi], b_frag[ni], acc[mi][ni], 0, 0, 0);
        }
    }

    // ---- epilogue. C layout: col = l16 (-> n), row = quad*4 + reg (-> m).
    __syncthreads();  // all waves done reading As/Bs; reuse LDS
    float* wred = (float*)smem + wave * (64 * 20);  // 5120 B per wave

    float s2v[4];
#pragma unroll
    for (int ni = 0; ni < 4; ++ni)
        s2v[ni] = s2[n0 + wn + ni * 16 + l16];

#pragma unroll
    for (int mi = 0; mi < 4; ++mi) {
#pragma unroll
        for (int r = 0; r < 4; ++r) {
            const int rowL = mi * 16 + quad * 4 + r;
            const float xv = x2[m0 + wm + rowL];
            float sum = 0.f;
#pragma unroll
            for (int ni = 0; ni < 4; ++ni) {
                float d2 = xv + s2v[ni] - 2.0f * acc[mi][ni][r];
                d2 = fmaxf(d2, 0.f);
                sum += __expf(-sc * d2);
            }
            wred[rowL * 20 + l16] = sum;
        }
    }
    __syncthreads();  // order LDS writes before cross-lane reads

    float4 p0 = *(float4*)(wred + lane * 20 + 0);
    float4 p1 = *(float4*)(wred + lane * 20 + 4);
    float4 p2 = *(float4*)(wred + lane * 20 + 8);
    float4 p3 = *(float4*)(wred + lane * 20 + 12);
    float s = (p0.x + p0.y + p0.z + p0.w) + (p1.x + p1.y + p1.z + p1.w)
            + (p2.x + p2.y + p2.z + p2.w) + (p3.x + p3.y + p3.z + p3.w);
    atomicAdd(&rowsum[m0 + wm + lane], s);
}

// ---------------------------------------------------------------------------
__global__ void finalize_kernel(const float* __restrict__ rowsum,
                                const float* __restrict__ scale_p,
                                float* __restrict__ out, int M, int N, int Dv) {
    const int m = blockIdx.x * 256 + threadIdx.x;
    if (m < M) {
        const float sc = *scale_p;
        const float cst = -logf((float)N) + 0.5f * (float)Dv * logf(sc / 3.14159265358979f);
        out[m] = logf(rowsum[m]) + cst;
    }
}

// ---------------------------------------------------------------------------
extern "C" void kernel_launch(void* const* d_in, const int* in_sizes, int n_in,
                              void* d_out, int out_size, void* d_ws, size_t ws_size,
                              hipStream_t stream) {
    const float* X       = (const float*)d_in[0];
    const float* S       = (const float*)d_in[1];
    const float* scale_p = (const float*)d_in[2];
    float* out = (float*)d_out;

    const int M  = out_size;            // 8192
    const int Dv = in_sizes[0] / M;     // 512
    const int N  = in_sizes[1] / Dv;    // 8192

    char* ws = (char*)d_ws;
    __hip_bfloat16* Xb = (__hip_bfloat16*)ws;
    __hip_bfloat16* Sb = (__hip_bfloat16*)(ws + (size_t)M * Dv * 2);
    float* x2     = (float*)(ws + (size_t)M * Dv * 2 + (size_t)N * Dv * 2);
    float* s2     = x2 + M;
    float* rowsum = s2 + N;

    prep_kernel<<<512, 256, 0, stream>>>(X, S, Xb, Sb, x2, s2, rowsum, M, M + N, Dv);

    dim3 grid(M / BM, N / BN);
    if (Dv == 512)
        kde_gemm_kernel<512><<<grid, 256, 0, stream>>>(Xb, Sb, x2, s2, scale_p, rowsum, M, N, Dv);
    else
        kde_gemm_kernel<0><<<grid, 256, 0, stream>>>(Xb, Sb, x2, s2, scale_p, rowsum, M, N, Dv);

    finalize_kernel<<<(M + 255) / 256, 256, 0, stream>>>(rowsum, scale_p, out, M, N, Dv);
}

// Round 4
// 122.094 us; speedup vs baseline: 1.7348x; 1.1943x over previous
//
#include <hip/hip_runtime.h>
#include <hip/hip_bf16.h>
#include <hip/hip_fp8.h>
#include <math.h>

typedef __attribute__((ext_vector_type(4))) int   int4v;
typedef __attribute__((ext_vector_type(8))) int   int8v;
typedef __attribute__((ext_vector_type(4))) float f32x4;

#define BM 128
#define BN 128
#define BK 128   // fp8: one 16x16x128 MFMA consumes the whole staged K-slab

// ---------------------------------------------------------------------------
// prep: 512 blocks x 256 threads, grid-stride over all M+N rows, one wave per
// row per iteration. fp32 -> fp8 e4m3 (OCP) + exact fp32 ||row||^2.
// Also zeroes rowsum[M].
// ---------------------------------------------------------------------------
__global__ __launch_bounds__(256) void prep_kernel(
    const float* __restrict__ X, const float* __restrict__ S,
    unsigned char* __restrict__ Xq, unsigned char* __restrict__ Sq,
    float* __restrict__ x2, float* __restrict__ s2,
    float* __restrict__ rowsum, int M, int R, int Dv)
{
    const int gid  = blockIdx.x * 256 + threadIdx.x;
    const int nthr = gridDim.x * 256;

    for (int i = gid; i < M; i += nthr) rowsum[i] = 0.f;

    const int lane = threadIdx.x & 63;
    const int wid  = gid >> 6;
    const int nw   = nthr >> 6;

    for (int row = wid; row < R; row += nw) {
        const float* rp;
        unsigned char* op;
        float* sq;
        if (row < M) { rp = X + (size_t)row * Dv;       op = Xq + (size_t)row * Dv;       sq = x2 + row; }
        else         { rp = S + (size_t)(row - M) * Dv; op = Sq + (size_t)(row - M) * Dv; sq = s2 + (row - M); }

        float acc = 0.f;
        for (int k = lane * 8; k < Dv; k += 64 * 8) {
            float4 v0 = *(const float4*)(rp + k);
            float4 v1 = *(const float4*)(rp + k + 4);
            acc += v0.x * v0.x + v0.y * v0.y + v0.z * v0.z + v0.w * v0.w;
            acc += v1.x * v1.x + v1.y * v1.y + v1.z * v1.z + v1.w * v1.w;
            union { __hip_fp8_e4m3 h[8]; uint2 u; } pk;
            pk.h[0] = __hip_fp8_e4m3(v0.x);
            pk.h[1] = __hip_fp8_e4m3(v0.y);
            pk.h[2] = __hip_fp8_e4m3(v0.z);
            pk.h[3] = __hip_fp8_e4m3(v0.w);
            pk.h[4] = __hip_fp8_e4m3(v1.x);
            pk.h[5] = __hip_fp8_e4m3(v1.y);
            pk.h[6] = __hip_fp8_e4m3(v1.z);
            pk.h[7] = __hip_fp8_e4m3(v1.w);
            *(uint2*)(op + k) = pk.u;
        }
#pragma unroll
        for (int off = 1; off < 64; off <<= 1)
            acc += __shfl_xor(acc, off, 64);
        if (lane == 0) *sq = acc;
    }
}

// ---------------------------------------------------------------------------
// Fused fp8 GEMM + exp-reduce. 256 threads (4 waves 2x2), tile 128x128,
// BK=128, mfma_scale 16x16x128 f8f6f4 with unity E8M0 scales (0x7F = 2^0).
// LDS rows are 128 B = 8 chunks of 16 B, XOR-chunk-swizzled (phys = c^(row&7))
// -> staging satisfies the global_load_lds linear-lane rule AND fragment
// b128 reads are conflict-free (every bank covered exactly 2x per 16 lanes).
// A-frag layout assumed: lane holds row (lane&15), k = (lane>>4)*32 .. +32
// contiguous (the only layout consistent with per-lane MX-32 scale bytes).
// Epilogue identical to R3 (C/D layout is shape-determined).
// ---------------------------------------------------------------------------
template<int DVC>
__global__ __launch_bounds__(256, 3) void kde_gemm_kernel(
    const unsigned char* __restrict__ Xq,   // [M][D] fp8 e4m3
    const unsigned char* __restrict__ Sq,   // [N][D] fp8 e4m3
    const float* __restrict__ x2,
    const float* __restrict__ s2,
    const float* __restrict__ scale_p,
    float* __restrict__ rowsum,
    int M, int N, int Dv)
{
    const int D = DVC ? DVC : Dv;

    __shared__ char smem[32768];
    unsigned char* As = (unsigned char*)smem;            // [128][128] fp8 16 KB
    unsigned char* Bs = (unsigned char*)(smem + 16384);  // [128][128] fp8 16 KB

    const int tid  = threadIdx.x;
    const int wave = tid >> 6;
    const int lane = tid & 63;
    const int quad = lane >> 4;
    const int l16  = lane & 15;

    const int m0 = blockIdx.x * BM;
    const int n0 = blockIdx.y * BN;
    const int wm = (wave & 1) * 64;   // wave's 64x64 quadrant
    const int wn = (wave >> 1) * 64;

    const float sc = *scale_p;

    f32x4 acc[4][4] = {};

    // staging: round rd covers rows rd*32..rd*32+31 (128 B each). Thread t:
    // row = rd*32 + (t>>3), fetches GLOBAL 16B-chunk (t&7)^(row&7) into
    // physical slot t&7; LDS dest = rd*4096 + t*16 (linear in lane). ✓
    const int srow0 = wave * 8 + (lane >> 3);
    const int cg    = (lane & 7) ^ (lane >> 3);   // (row&7) == lane>>3
    const unsigned char* gA = Xq + (size_t)(m0 + srow0) * D + cg * 16;
    const unsigned char* gB = Sq + (size_t)(n0 + srow0) * D + cg * 16;

#pragma unroll
    for (int k0 = 0; k0 < D; k0 += BK) {
        __syncthreads();  // prev iter's ds_reads done before overwrite
#pragma unroll
        for (int rd = 0; rd < 4; ++rd)
            __builtin_amdgcn_global_load_lds(
                (const __attribute__((address_space(1))) void*)(gA + (size_t)rd * 32 * D + k0),
                (__attribute__((address_space(3))) void*)(smem + rd * 4096 + wave * 1024),
                16, 0, 0);
#pragma unroll
        for (int rd = 0; rd < 4; ++rd)
            __builtin_amdgcn_global_load_lds(
                (const __attribute__((address_space(1))) void*)(gB + (size_t)rd * 32 * D + k0),
                (__attribute__((address_space(3))) void*)(smem + 16384 + rd * 4096 + wave * 1024),
                16, 0, 0);
        __syncthreads();  // staging drained

        const int e = l16 & 7;
        int8v a_frag[4], b_frag[4];
#pragma unroll
        for (int mi = 0; mi < 4; ++mi) {
            const unsigned char* rowp = As + (wm + mi * 16 + l16) * 128;
            int4v lo = *(const int4v*)(rowp + ((2 * quad)     ^ e) * 16);
            int4v hi = *(const int4v*)(rowp + ((2 * quad + 1) ^ e) * 16);
            a_frag[mi] = (int8v){lo.x, lo.y, lo.z, lo.w, hi.x, hi.y, hi.z, hi.w};
        }
#pragma unroll
        for (int ni = 0; ni < 4; ++ni) {
            const unsigned char* rowp = Bs + (wn + ni * 16 + l16) * 128;
            int4v lo = *(const int4v*)(rowp + ((2 * quad)     ^ e) * 16);
            int4v hi = *(const int4v*)(rowp + ((2 * quad + 1) ^ e) * 16);
            b_frag[ni] = (int8v){lo.x, lo.y, lo.z, lo.w, hi.x, hi.y, hi.z, hi.w};
        }
#pragma unroll
        for (int mi = 0; mi < 4; ++mi)
#pragma unroll
            for (int ni = 0; ni < 4; ++ni)
                acc[mi][ni] = __builtin_amdgcn_mfma_scale_f32_16x16x128_f8f6f4(
                    a_frag[mi], b_frag[ni], acc[mi][ni],
                    0, 0,                     // cbsz=fp8 e4m3, blgp=fp8 e4m3
                    0, 0x7F7F7F7F,            // A scales: byte0, E8M0 127 = 1.0
                    0, 0x7F7F7F7F);           // B scales: unity
    }

    // ---- epilogue. C layout: col = l16 (-> n), row = quad*4 + reg (-> m).
    __syncthreads();  // all waves done reading As/Bs; reuse LDS
    float* wred = (float*)smem + wave * (64 * 20);  // 5120 B per wave

    float s2v[4];
#pragma unroll
    for (int ni = 0; ni < 4; ++ni)
        s2v[ni] = s2[n0 + wn + ni * 16 + l16];

#pragma unroll
    for (int mi = 0; mi < 4; ++mi) {
#pragma unroll
        for (int r = 0; r < 4; ++r) {
            const int rowL = mi * 16 + quad * 4 + r;
            const float xv = x2[m0 + wm + rowL];
            float sum = 0.f;
#pragma unroll
            for (int ni = 0; ni < 4; ++ni) {
                float d2 = xv + s2v[ni] - 2.0f * acc[mi][ni][r];
                d2 = fmaxf(d2, 0.f);
                sum += __expf(-sc * d2);
            }
            wred[rowL * 20 + l16] = sum;
        }
    }
    __syncthreads();  // order LDS writes before cross-lane reads

    float4 p0 = *(float4*)(wred + lane * 20 + 0);
    float4 p1 = *(float4*)(wred + lane * 20 + 4);
    float4 p2 = *(float4*)(wred + lane * 20 + 8);
    float4 p3 = *(float4*)(wred + lane * 20 + 12);
    float s = (p0.x + p0.y + p0.z + p0.w) + (p1.x + p1.y + p1.z + p1.w)
            + (p2.x + p2.y + p2.z + p2.w) + (p3.x + p3.y + p3.z + p3.w);
    atomicAdd(&rowsum[m0 + wm + lane], s);
}

// ---------------------------------------------------------------------------
__global__ void finalize_kernel(const float* __restrict__ rowsum,
                                const float* __restrict__ scale_p,
                                float* __restrict__ out, int M, int N, int Dv) {
    const int m = blockIdx.x * 256 + threadIdx.x;
    if (m < M) {
        const float sc = *scale_p;
        const float cst = -logf((float)N) + 0.5f * (float)Dv * logf(sc / 3.14159265358979f);
        out[m] = logf(rowsum[m]) + cst;
    }
}

// ---------------------------------------------------------------------------
extern "C" void kernel_launch(void* const* d_in, const int* in_sizes, int n_in,
                              void* d_out, int out_size, void* d_ws, size_t ws_size,
                              hipStream_t stream) {
    const float* X       = (const float*)d_in[0];
    const float* S       = (const float*)d_in[1];
    const float* scale_p = (const float*)d_in[2];
    float* out = (float*)d_out;

    const int M  = out_size;            // 8192
    const int Dv = in_sizes[0] / M;     // 512
    const int N  = in_sizes[1] / Dv;    // 8192

    char* ws = (char*)d_ws;
    unsigned char* Xq = (unsigned char*)ws;
    unsigned char* Sq = (unsigned char*)(ws + (size_t)M * Dv);
    float* x2     = (float*)(ws + (size_t)M * Dv + (size_t)N * Dv);
    float* s2     = x2 + M;
    float* rowsum = s2 + N;

    prep_kernel<<<512, 256, 0, stream>>>(X, S, Xq, Sq, x2, s2, rowsum, M, M + N, Dv);

    dim3 grid(M / BM, N / BN);
    if (Dv == 512)
        kde_gemm_kernel<512><<<grid, 256, 0, stream>>>(Xq, Sq, x2, s2, scale_p, rowsum, M, N, Dv);
    else
        kde_gemm_kernel<0><<<grid, 256, 0, stream>>>(Xq, Sq, x2, s2, scale_p, rowsum, M, N, Dv);

    finalize_kernel<<<(M + 255) / 256, 256, 0, stream>>>(rowsum, scale_p, out, M, N, Dv);
}